// Round 5
// baseline (135.293 us; speedup 1.0000x reference)
//
#include <hip/hip_runtime.h>
#include <math.h>

// SSIM loss, fp32 in, B=16 C=3 H=W=512, 11x11 Gaussian (sigma=1.5), zero pad.
// R14: carry-accumulate vconv + deep block queue.
//  - vconv split via MFMA C-accumulate: out_u = MFMA(Wv_lo, H_u) +
//    MFMA(Wv_hi, H_{u+1}); H chunks consumed as produced -> Ht is a SINGLE
//    16-row buffer (12.3 KB LDS, was 29 KB 2-chunk ring). No cross-chunk LDS
//    dependency; barrier-free main body (same-wave producer/consumer).
//  - TYS=64 -> grid 3072 blocks = ~12 blocks/CU of work vs ~5 resident:
//    real block queue (R13's grid 1536 ~= resident capacity -> single-cohort,
//    duration = one block's latency incl. ramp/tail).
//  - 2-slot load ring, re-issued AFTER consumption + sched_barrier(0) pin ->
//    ~2-iteration latency cover the compiler can't sink away (R12/R13 sank
//    loads: VGPR_Count stayed 44 both rounds).
// Math identical to R10-R13 (S=x+y, D=x-y planes, f16 pipeline, cv fixup).
// gfx950 v_mfma_f32_16x16x32_f16 layouts (verified R10-R13 pass):
//   A[i][k]: lane = i + 16*(k/8), elem = k%8
//   B[k][j]: lane = j + 16*(k/8), elem = k%8
//   D[r][c]: lane = c + 16*(r/4), reg  = r%4
// vconv weights: A1[u][k] = w[k-u] (k<16 else 0), A2[u][k] = w[k+16-u]
// (k<16 else 0); B k>=16 lanes re-read rows k-16 (finite) x zero weight.

#define IMG_W 512
#define IMG_H 512
#define PLANES 48
#define TX 64
#define TYS 64
#define RAD 5
#define NT 256
#define GDX (IMG_W / TX)            // 8
#define GDY (IMG_H / TYS)           // 8
#define NBLK (GDX * GDY * PLANES)   // 3072
#define NCH 5                       // hconv 16-row chunks (80 H rows)
#define CSTR 24                     // Ht col stride, f16 (48 B; 12 dw -> 8-bank spread)
#define PSTR (TX * CSTR)            // Ht plane stride, f16 (1536)
#define NUMREC (IMG_W * IMG_H * 4)  // SRD num_records (bytes)
#define CHSTEP (16 * IMG_W * 4)     // voffset step per 16-row chunk (32768)
#define INVW  0.26601181f           // 1 / sum(exp(-(k-5)^2/4.5))
#define GC2   0.32059890f           // (1/4.5) * log2(e)

typedef _Float16 h2 __attribute__((ext_vector_type(2)));
typedef _Float16 h4 __attribute__((ext_vector_type(4)));
typedef _Float16 h8 __attribute__((ext_vector_type(8)));
typedef float f32x4 __attribute__((ext_vector_type(4)));
typedef int i32x4 __attribute__((ext_vector_type(4)));

// CK-style direct binding to the raw buffer-load intrinsic: hardware
// bounds-check vs num_records; OOB lanes read 0. Compiler tracks vmcnt.
__device__ f32x4 buf_ld_x4(i32x4 srsrc, int voffset, int soffset, int aux)
    __asm("llvm.amdgcn.raw.buffer.load.v4f32");

__device__ __forceinline__ i32x4 make_srd(const float* p) {
    union { i32x4 v; struct { const float* p; unsigned rng; unsigned cfg; } s; } u;
    u.s.p = p; u.s.rng = NUMREC; u.s.cfg = 0x00020000u;
    return u.v;
}

__device__ __forceinline__ float exp2_fast(float a) {
#if __has_builtin(__builtin_amdgcn_exp2f)
    return __builtin_amdgcn_exp2f(a);
#else
    return exp2f(a);
#endif
}

// Normalized f32 Gaussian weight w[idx], idx in [0,10], else 0.
__device__ __forceinline__ float wbandf(int idx) {
    const float fd = (float)(idx - 5);
    const float g = exp2_fast(-(fd * fd) * GC2) * INVW;
    return ((unsigned)idx <= 10u) ? g : 0.f;
}

__device__ __forceinline__ h2 pkrtz(float a, float b) {
    auto t = __builtin_amdgcn_cvt_pkrtz(a, b);
    h2 r;
    __builtin_memcpy(&r, &t, sizeof(r));
    return r;
}

__device__ __forceinline__ h4 pack4(f32x4 a) {
    const h2 lo = pkrtz(a[0], a[1]), hi = pkrtz(a[2], a[3]);
    h4 v;
    v[0] = lo.x; v[1] = lo.y; v[2] = hi.x; v[3] = hi.y;
    return v;
}

// One 16-row hconv chunk: regs -> s/d/s2/d2 MFMA -> transposed f16 Ht.
__device__ __forceinline__ void hconv_chunk(
    f32x4 xa, f32x4 xb, f32x4 ya, f32x4 yb, h8 whB,
    _Float16* wp)    // = Ht + col*CSTR + 4*q
{
    const f32x4 zz = {0.f, 0.f, 0.f, 0.f};
    const h2 xh0 = pkrtz(xa[0], xa[1]), xh1 = pkrtz(xa[2], xa[3]);
    const h2 xh2 = pkrtz(xb[0], xb[1]), xh3 = pkrtz(xb[2], xb[3]);
    const h2 yh0 = pkrtz(ya[0], ya[1]), yh1 = pkrtz(ya[2], ya[3]);
    const h2 yh2 = pkrtz(yb[0], yb[1]), yh3 = pkrtz(yb[2], yb[3]);
    const h2 s0 = xh0 + yh0, s1 = xh1 + yh1, s2 = xh2 + yh2, s3 = xh3 + yh3;
    const h2 d0 = xh0 - yh0, d1 = xh1 - yh1, d2 = xh2 - yh2, d3 = xh3 - yh3;
    h8 sA, dA;
    sA[0] = s0.x; sA[1] = s0.y; sA[2] = s1.x; sA[3] = s1.y;
    sA[4] = s2.x; sA[5] = s2.y; sA[6] = s3.x; sA[7] = s3.y;
    dA[0] = d0.x; dA[1] = d0.y; dA[2] = d1.x; dA[3] = d1.y;
    dA[4] = d2.x; dA[5] = d2.y; dA[6] = d3.x; dA[7] = d3.y;
    const h8 s2A = sA * sA;                       // v_pk_mul_f16
    const h8 d2A = dA * dA;
    const f32x4 hS  = __builtin_amdgcn_mfma_f32_16x16x32_f16(sA,  whB, zz, 0, 0, 0);
    const f32x4 hD  = __builtin_amdgcn_mfma_f32_16x16x32_f16(dA,  whB, zz, 0, 0, 0);
    const f32x4 hS2 = __builtin_amdgcn_mfma_f32_16x16x32_f16(s2A, whB, zz, 0, 0, 0);
    const f32x4 hD2 = __builtin_amdgcn_mfma_f32_16x16x32_f16(d2A, whB, zz, 0, 0, 0);
    *(h4*)(wp + 0 * PSTR) = pack4(hS);            // ds_write_b64
    *(h4*)(wp + 1 * PSTR) = pack4(hD);
    *(h4*)(wp + 2 * PSTR) = pack4(hS2);
    *(h4*)(wp + 3 * PSTR) = pack4(hD2);
}

// SSIM map for one completed out-chunk (4 rows of one col per lane).
__device__ __forceinline__ float mapsum(f32x4 aS, f32x4 aD, f32x4 aS2, f32x4 aD2,
                                        float cv)
{
    float local = 0.f;
    #pragma unroll
    for (int r = 0; r < 4; ++r) {
        const float mS = aS[r]  * cv, mD = aD[r]  * cv;
        const float eS = aS2[r] * cv, eD = aD2[r] * cv;
        const float ms2 = mS * mS, md2 = mD * mD;
        const float Pm = 0.5f * (ms2 - md2);   // = 2*mu_x*mu_y
        const float Qm = 0.5f * (ms2 + md2);   // = mu_x^2 + mu_y^2
        const float Pe = 0.5f * (eS - eD);     // = 2*E[xy]
        const float Qe = 0.5f * (eS + eD);     // = E[x^2 + y^2]
        const float c1 = 1e-4f, c2 = 9e-4f;
        const float num = (Pm + c1) * (Pe - Pm + c2);
        const float den = (Qm + c1) * (Qe - Qm + c2) + 1e-8f;
        local += num * __builtin_amdgcn_rcpf(den);
    }
    return local;
}

#define MFMA16(A, B, C) __builtin_amdgcn_mfma_f32_16x16x32_f16((A), (B), (C), 0, 0, 0)

#define VSTART(ACC) do {                         \
    ACC[0] = MFMA16(wvA1, B0, zz);               \
    ACC[1] = MFMA16(wvA1, B1, zz);               \
    ACC[2] = MFMA16(wvA1, B2, zz);               \
    ACC[3] = MFMA16(wvA1, B3, zz);               \
} while (0)

#define VFINISH(ACC) do {                        \
    const f32x4 fS  = MFMA16(wvA2, B0, ACC[0]);  \
    const f32x4 fD  = MFMA16(wvA2, B1, ACC[1]);  \
    const f32x4 fS2 = MFMA16(wvA2, B2, ACC[2]);  \
    const f32x4 fD2 = MFMA16(wvA2, B3, ACC[3]);  \
    local += mapsum(fS, fD, fS2, fD2, cv);       \
} while (0)

__global__ __launch_bounds__(NT, 5) void ssim_tile_kernel(
    const float* __restrict__ x, const float* __restrict__ y,
    float* __restrict__ partials)
{
    __shared__ __align__(16) _Float16 Ht[4 * PSTR];   // 12288 B
    __shared__ float wave_sums[NT / 64];

    const int tid = threadIdx.x;
    const int l = tid & 63, wid = tid >> 6;
    const int q = l >> 4, fc = l & 15;

    const int plane = blockIdx.z;
    const i32x4 srdx = make_srd(x + (size_t)plane * IMG_H * IMG_W);
    const i32x4 srdy = make_srd(y + (size_t)plane * IMG_H * IMG_W);
    const int C0 = blockIdx.x * TX;
    const int R0 = blockIdx.y * TYS;
    const int c0 = 16 * wid;
    const int col = c0 + fc;
    const int gcol = C0 + c0 - 8 + 8 * q;       // A-frag global col start
    const int gr0 = R0 - RAD + fc;              // chunk-0 global row
    // Row OOB -> voffset outside [0,NUMREC) -> HW returns 0.
    // Col OOB lanes (gcol=-8 or 512): permanently-OOB voffset.
    int voff = ((unsigned)gcol < (unsigned)IMG_W)
             ? ((gr0 << 11) + (gcol << 2)) : 0x60000000;

    // ---- Prologue: issue chunks 0,1 into ring slots 0,1 ----
    f32x4 LXA[2], LXB[2], LYA[2], LYB[2];
    #pragma unroll
    for (int cpl = 0; cpl < 2; ++cpl) {
        LXA[cpl] = buf_ld_x4(srdx, voff, 0, 0);
        LXB[cpl] = buf_ld_x4(srdx, voff, 16, 0);
        LYA[cpl] = buf_ld_x4(srdy, voff, 0, 0);
        LYB[cpl] = buf_ld_x4(srdy, voff, 16, 0);
        voff += CHSTEP;
    }
    __builtin_amdgcn_sched_barrier(0);

    // ---- Weight setup (under the in-flight loads) ----
    float s2w = 0.f;
    #pragma unroll
    for (int k = 0; k <= 10; ++k) s2w += (float)(_Float16)wbandf(k);
    const float cv = 1.f / (s2w * s2w);

    h8 whB, wvA1, wvA2;
    #pragma unroll
    for (int e = 0; e < 8; ++e) {
        const int k = 8 * q + e;
        whB[e]  = (_Float16)wbandf(k - fc - 3);                     // hconv band
        wvA1[e] = (_Float16)((k < 16) ? wbandf(k - fc)      : 0.f); // vconv lo
        wvA2[e] = (_Float16)((k < 16) ? wbandf(k + 16 - fc) : 0.f); // vconv hi
    }

    _Float16* const hw = Ht + col * CSTR + 4 * q;            // hconv write base
    const _Float16* const rbase = Ht + col * CSTR + 8 * (q & 1); // vconv read base

    f32x4 acc0[4], acc1[4];                                  // out-chunk parity accs
    const f32x4 zz = {0.f, 0.f, 0.f, 0.f};
    float local = 0.f;

    // ---- Main loop over hconv chunks c; Ht holds chunk c-1 at loop top ----
    #pragma unroll
    for (int c = 0; c < NCH; ++c) {
        if (c >= 1) {
            const h8 B0 = *(const h8*)(rbase + 0 * PSTR);    // ds_read_b128 x4
            const h8 B1 = *(const h8*)(rbase + 1 * PSTR);
            const h8 B2 = *(const h8*)(rbase + 2 * PSTR);
            const h8 B3 = *(const h8*)(rbase + 3 * PSTR);
            if (c & 1) {
                if (c >= 2) VFINISH(acc1);                   // complete out c-2
                VSTART(acc0);                                // start out c-1
            } else {
                if (c >= 2) VFINISH(acc0);
                VSTART(acc1);
            }
        }
        // hconv chunk c (overwrites Ht chunk c-1 AFTER the reads above;
        // same-wave DS ops execute in order)
        hconv_chunk(LXA[c & 1], LXB[c & 1], LYA[c & 1], LYB[c & 1], whB, hw);
        // re-issue freed ring slot with chunk c+2
        if (c + 2 < NCH) {
            LXA[c & 1] = buf_ld_x4(srdx, voff, 0, 0);
            LXB[c & 1] = buf_ld_x4(srdx, voff, 16, 0);
            LYA[c & 1] = buf_ld_x4(srdy, voff, 0, 0);
            LYB[c & 1] = buf_ld_x4(srdy, voff, 16, 0);
            voff += CHSTEP;
        }
        __builtin_amdgcn_sched_barrier(0);   // pin load issue (no sinking)
    }

    // ---- Epilogue: Ht holds chunk NCH-1=4; complete out-chunk 3 (acc1) ----
    {
        const h8 B0 = *(const h8*)(rbase + 0 * PSTR);
        const h8 B1 = *(const h8*)(rbase + 1 * PSTR);
        const h8 B2 = *(const h8*)(rbase + 2 * PSTR);
        const h8 B3 = *(const h8*)(rbase + 3 * PSTR);
        VFINISH(acc1);
    }

    // ---- Block reduction -> one partial per block ----
    #pragma unroll
    for (int off = 32; off > 0; off >>= 1)
        local += __shfl_down(local, off, 64);
    if (l == 0) wave_sums[wid] = local;
    __syncthreads();
    if (tid == 0) {
        const float s = wave_sums[0] + wave_sums[1] + wave_sums[2] + wave_sums[3];
        const int bid = blockIdx.x + GDX * (blockIdx.y + GDY * blockIdx.z);
        partials[bid] = s;
    }
}

__global__ __launch_bounds__(NT) void ssim_finalize_kernel(
    const float* __restrict__ partials, float* __restrict__ out)
{
    const int tid = threadIdx.x;
    double s = 0.0;
    #pragma unroll 4
    for (int i = tid; i < NBLK; i += NT) s += (double)partials[i];
    #pragma unroll
    for (int off = 32; off > 0; off >>= 1)
        s += __shfl_down(s, off, 64);
    __shared__ double ws_[NT / 64];
    const int lane = tid & 63, wv = tid >> 6;
    if (lane == 0) ws_[wv] = s;
    __syncthreads();
    if (tid == 0) {
        const double t = ws_[0] + ws_[1] + ws_[2] + ws_[3];
        const double n = (double)PLANES * IMG_H * IMG_W;
        out[0] = (float)(1.0 - t / n);
    }
}

extern "C" void kernel_launch(void* const* d_in, const int* in_sizes, int n_in,
                              void* d_out, int out_size, void* d_ws, size_t ws_size,
                              hipStream_t stream)
{
    const float* x = (const float*)d_in[0];
    const float* y = (const float*)d_in[1];
    float* out = (float*)d_out;
    float* partials = (float*)d_ws;   // NBLK floats, fully overwritten each call

    dim3 grid(GDX, GDY, PLANES);
    ssim_tile_kernel<<<grid, NT, 0, stream>>>(x, y, partials);
    ssim_finalize_kernel<<<1, NT, 0, stream>>>(partials, out);
}